// Round 7
// baseline (277.836 us; speedup 1.0000x reference)
//
#include <hip/hip_runtime.h>
#include <math.h>

// ---------------------------------------------------------------------------
// Encoder_Flows on MI355X — 5 dispatches, barrier-free direct-fragment MFMA.
//   prep  : weight fp32->bf16 cvt + proj1 (YT1 = (flow[:1024]@wl1^T)^T) + scalar
//   main_L: 1024 blocks x 32 rows. All blocks: X@wr^T (direct-frag, NO k-loop
//           barriers) + bias (+agg for rows<1024 via scan-GEMM on YT_L) +
//           row-L2-norm -> x_L (bf16) [L4: relu -> fp32 out].
//           Head blocks (bid<32) additionally compute next layer's proj
//           (x_L[0:1024]@wl_{L+1}^T)^T -> YT_{L+1} through a swizzled LDS xbuf.
// Rationale (R6 post-mortem): reg-staged LDS GEMM forces vmcnt(0) drains at
// every barrier -> latency-bound at 1 TB/s. Direct-frag loads let the
// compiler pipeline loads across K-steps; weights are L2-resident.
// ---------------------------------------------------------------------------

typedef __attribute__((ext_vector_type(8))) short short8;
typedef __attribute__((ext_vector_type(4))) float f32x4;

constexpr int NROWS = 32768;
constexpr int KROWS = 1024;

static __device__ __forceinline__ unsigned short f2bf(float f) {
    unsigned int u = __float_as_uint(f);
    return (unsigned short)((u + 0x7fffu + ((u >> 16) & 1u)) >> 16);
}

static __device__ __forceinline__ short8 pack8(float4 x0, float4 x1) {
    short8 s;
    s[0] = (short)f2bf(x0.x); s[1] = (short)f2bf(x0.y);
    s[2] = (short)f2bf(x0.z); s[3] = (short)f2bf(x0.w);
    s[4] = (short)f2bf(x1.x); s[5] = (short)f2bf(x1.y);
    s[6] = (short)f2bf(x1.z); s[7] = (short)f2bf(x1.w);
    return s;
}

// ---------------------------------------------------------------------------
// Barrier-free direct-fragment GEMM over a 32-row tile.
//   acc[fi][fj] += A[32 x DIN] @ W[DOUT x DIN]^T   (block tile, wave-split)
//   AK: 0 = A global bf16 (base pre-offset to row 0 of tile)
//       1 = A global fp32  (cvt in-reg)
//       2 = A LDS bf16, XOR-swizzled (byte ^= (row&7)<<4), stride DIN
//   BFP32: W fp32 (cvt in-reg) vs bf16.
// DOUT=128: WN=2,WM=2,FM=1 ; DOUT=256: WN=4,WM=1,FM=2.
// ---------------------------------------------------------------------------
template<int DIN, int DOUT, int AK, bool BFP32>
__device__ __forceinline__ void gemm_direct(const void* __restrict__ Av,
    const void* __restrict__ Wv, f32x4 (&acc)[DOUT / 128][4], int t)
{
    constexpr int WN = DOUT / 64, WM = 4 / WN, FM = DOUT / 128;
    const int wv = t >> 6, lane = t & 63, wr_ = wv / WN, wc = wv % WN;
#pragma unroll
    for (int fi = 0; fi < FM; ++fi)
#pragma unroll
        for (int fj = 0; fj < 4; ++fj) acc[fi][fj] = (f32x4){0.f, 0.f, 0.f, 0.f};

    auto body = [&](int kt) {
        const int k0 = kt * 32 + ((lane >> 4) << 3);
        short8 a[FM];
#pragma unroll
        for (int fi = 0; fi < FM; ++fi) {
            const int rA = wr_ * (32 / WM) + fi * 16 + (lane & 15);
            if constexpr (AK == 1) {
                const float* p = (const float*)Av + (size_t)rA * DIN + k0;
                a[fi] = pack8(*reinterpret_cast<const float4*>(p),
                              *reinterpret_cast<const float4*>(p + 4));
            } else if constexpr (AK == 2) {
                const int off = ((rA * DIN + k0) * 2) ^ ((rA & 7) << 4);
                a[fi] = *reinterpret_cast<const short8*>((const char*)Av + off);
            } else {
                a[fi] = *reinterpret_cast<const short8*>(
                    (const unsigned short*)Av + (size_t)rA * DIN + k0);
            }
        }
        short8 b[4];
#pragma unroll
        for (int fj = 0; fj < 4; ++fj) {
            const int o = wc * 64 + fj * 16 + (lane & 15);
            if constexpr (BFP32) {
                const float* p = (const float*)Wv + (size_t)o * DIN + k0;
                b[fj] = pack8(*reinterpret_cast<const float4*>(p),
                              *reinterpret_cast<const float4*>(p + 4));
            } else {
                b[fj] = *reinterpret_cast<const short8*>(
                    (const unsigned short*)Wv + (size_t)o * DIN + k0);
            }
        }
#pragma unroll
        for (int fi = 0; fi < FM; ++fi)
#pragma unroll
            for (int fj = 0; fj < 4; ++fj)
                acc[fi][fj] = __builtin_amdgcn_mfma_f32_16x16x32_bf16(
                    a[fi], b[fj], acc[fi][fj], 0, 0, 0);
    };
    if constexpr (DIN >= 512) {
#pragma unroll 2
        for (int kt = 0; kt < DIN / 32; ++kt) body(kt);
    } else {
#pragma unroll
        for (int kt = 0; kt < DIN / 32; ++kt) body(kt);
    }
}

// ---- scan-GEMM: agg = (L @ Y)/cnt from Y^T (DOUT x 1024), direct frags ----
template<int DOUT>
__device__ __forceinline__ void scan_agg(const unsigned short* __restrict__ YT,
    int i0, f32x4 (&agg)[DOUT / 128][4], int t)
{
    constexpr int WN = DOUT / 64, WM = 4 / WN, FM = DOUT / 128;
    const int wv = t >> 6, lane = t & 63, wr_ = wv / WN, wc = wv % WN;
#pragma unroll
    for (int fi = 0; fi < FM; ++fi)
#pragma unroll
        for (int fj = 0; fj < 4; ++fj) agg[fi][fj] = (f32x4){0.f, 0.f, 0.f, 0.f};
    const int nt = (i0 + 95) >> 6;              // ceil((i0+32)/64)
    for (int kt = 0; kt < nt; ++kt) {
#pragma unroll
        for (int kk = 0; kk < 2; ++kk) {
            const int jb = kt * 64 + kk * 32 + ((lane >> 4) << 3);
            short8 a[FM], b[4];
#pragma unroll
            for (int fi = 0; fi < FM; ++fi) {
                const int irow = i0 + wr_ * (32 / WM) + fi * 16 + (lane & 15);
#pragma unroll
                for (int e = 0; e < 8; ++e)
                    a[fi][e] = (short)((jb + e < irow) ? 0x3F80 : 0);
            }
#pragma unroll
            for (int fj = 0; fj < 4; ++fj) {
                const int o = wc * 64 + fj * 16 + (lane & 15);
                b[fj] = *reinterpret_cast<const short8*>(YT + (size_t)o * KROWS + jb);
            }
#pragma unroll
            for (int fi = 0; fi < FM; ++fi)
#pragma unroll
                for (int fj = 0; fj < 4; ++fj)
                    agg[fi][fj] = __builtin_amdgcn_mfma_f32_16x16x32_bf16(
                        a[fi], b[fj], agg[fi][fj], 0, 0, 0);
        }
    }
#pragma unroll
    for (int fi = 0; fi < FM; ++fi)
#pragma unroll
        for (int reg = 0; reg < 4; ++reg) {
            const int i_abs = i0 + wr_ * (32 / WM) + fi * 16 + ((lane >> 4) << 2) + reg;
            const float inv = 1.0f / (float)(i_abs > 1 ? i_abs : 1);
#pragma unroll
            for (int fj = 0; fj < 4; ++fj) agg[fi][fj][reg] *= inv;
        }
}

// ---- bias(+agg) add, row L2-norm across block -> inv scale ----------------
template<int DOUT>
__device__ __forceinline__ void norm_rows(f32x4 (&acc)[DOUT / 128][4],
    const float* __restrict__ bias, const f32x4 (*agg)[4],
    float* ssred, int t, float (&inv)[DOUT / 128][4])
{
    constexpr int WN = DOUT / 64, WM = 4 / WN, FM = DOUT / 128;
    const int wv = t >> 6, lane = t & 63, wr_ = wv / WN, wc = wv % WN;
    float bb[4];
#pragma unroll
    for (int fj = 0; fj < 4; ++fj) bb[fj] = bias[wc * 64 + fj * 16 + (lane & 15)];
#pragma unroll
    for (int fi = 0; fi < FM; ++fi)
#pragma unroll
        for (int fj = 0; fj < 4; ++fj)
#pragma unroll
            for (int reg = 0; reg < 4; ++reg) {
                float v = acc[fi][fj][reg] + bb[fj];
                if (agg) v += agg[fi][fj][reg];
                acc[fi][fj][reg] = v;
            }
#pragma unroll
    for (int fi = 0; fi < FM; ++fi)
#pragma unroll
        for (int reg = 0; reg < 4; ++reg) {
            float s = 0.f;
#pragma unroll
            for (int fj = 0; fj < 4; ++fj) { float v = acc[fi][fj][reg]; s += v * v; }
#pragma unroll
            for (int m = 8; m >= 1; m >>= 1) s += __shfl_xor(s, m);
            if ((lane & 15) == 0) {
                const int rl = wr_ * (32 / WM) + fi * 16 + ((lane >> 4) << 2) + reg;
                ssred[wc * 32 + rl] = s;
            }
        }
    __syncthreads();
#pragma unroll
    for (int fi = 0; fi < FM; ++fi)
#pragma unroll
        for (int reg = 0; reg < 4; ++reg) {
            const int rl = wr_ * (32 / WM) + fi * 16 + ((lane >> 4) << 2) + reg;
            float s = 0.f;
#pragma unroll
            for (int c = 0; c < WN; ++c) s += ssred[c * 32 + rl];
            inv[fi][reg] = 1.0f / fmaxf(sqrtf(s), 1e-12f);
        }
}

// ---------------------------------------------------------------------------
// prep: blocks [0,32) proj1 (direct-frag, fp32 A and B) -> YT1 bf16;
//       blocks [32,352) weight cvt; tuple scalar.
// ---------------------------------------------------------------------------
__global__ __launch_bounds__(256, 2)
void prep_kernel(const float* __restrict__ flow, const float* __restrict__ wl1,
                 const float* __restrict__ wr1, const float* __restrict__ wl2,
                 const float* __restrict__ wr2, const float* __restrict__ wl3,
                 const float* __restrict__ wr3, const float* __restrict__ wl4,
                 const float* __restrict__ wr4,
                 unsigned short* __restrict__ wbf,
                 unsigned short* __restrict__ YT1, float* __restrict__ outscalar)
{
    const int t = threadIdx.x, bid = blockIdx.x;
    if (bid >= 32) {
        if (bid == 32 && t == 0) outscalar[0] = 1.0f;
        int g = (bid - 32) * 1024 + t * 4;
        const float* src; int off;
        if      (g < 131072) { src = wr1; off = g; }
        else if (g < 163840) { src = wl2; off = g - 131072; }
        else if (g < 196608) { src = wr2; off = g - 163840; }
        else if (g < 229376) { src = wl3; off = g - 196608; }
        else if (g < 262144) { src = wr3; off = g - 229376; }
        else if (g < 294912) { src = wl4; off = g - 262144; }
        else                 { src = wr4; off = g - 294912; }
        float4 v = *reinterpret_cast<const float4*>(src + off);
        ushort4 o4;
        o4.x = f2bf(v.x); o4.y = f2bf(v.y); o4.z = f2bf(v.z); o4.w = f2bf(v.w);
        *reinterpret_cast<ushort4*>(wbf + g) = o4;
        return;
    }
    const int i0 = bid * 32, wv = t >> 6, lane = t & 63;
    const int wr_ = wv >> 1, wc = wv & 1;      // DOUT=128 mapping
    f32x4 acc[1][4];
    gemm_direct<1024, 128, 1, true>(flow + (size_t)i0 * 1024, wl1, acc, t);
#pragma unroll
    for (int fj = 0; fj < 4; ++fj) {
        const int rl0 = wr_ * 16 + ((lane >> 4) << 2);
        const int cl  = wc * 64 + fj * 16 + (lane & 15);
        ushort4 y;
        y.x = f2bf(acc[0][fj][0]); y.y = f2bf(acc[0][fj][1]);
        y.z = f2bf(acc[0][fj][2]); y.w = f2bf(acc[0][fj][3]);
        *reinterpret_cast<ushort4*>(YT1 + (size_t)cl * KROWS + i0 + rl0) = y;
    }
}

// ---------------------------------------------------------------------------
// main_L: 1024 blocks x 32 rows. GEMM + (head: scan agg) + norm + store;
//         head blocks also produce YT_{L+1} via xbuf.
// ---------------------------------------------------------------------------
template<int DIN, int DOUT, int DNEXT, bool AFP32, int MODE>
__global__ __launch_bounds__(256, 4)
void main_kernel(const void* __restrict__ Xv,
    const unsigned short* __restrict__ W, const float* __restrict__ bias,
    const unsigned short* __restrict__ YT,
    const unsigned short* __restrict__ Wnext,
    unsigned short* __restrict__ xdst, float* __restrict__ outf,
    unsigned short* __restrict__ YTnext)
{
    constexpr int WN = DOUT / 64, WM = 4 / WN, FM = DOUT / 128;
    __shared__ unsigned short xbuf[32 * 256];
    __shared__ float ssred[128];
    const int t = threadIdx.x, wv = t >> 6, lane = t & 63;
    const int wr_ = wv / WN, wc = wv % WN;
    const int i0 = blockIdx.x * 32;
    const bool head = (i0 < KROWS);

    f32x4 acc[FM][4];
    if constexpr (AFP32)
        gemm_direct<DIN, DOUT, 1, false>(
            (const float*)Xv + (size_t)i0 * DIN, W, acc, t);
    else
        gemm_direct<DIN, DOUT, 0, false>(
            (const unsigned short*)Xv + (size_t)i0 * DIN, W, acc, t);

    f32x4 agg[FM][4];
    if (head) scan_agg<DOUT>(YT, i0, agg, t);

    float inv[FM][4];
    norm_rows<DOUT>(acc, bias, head ? &agg[0] : nullptr, ssred, t, inv);

#pragma unroll
    for (int fi = 0; fi < FM; ++fi)
#pragma unroll
        for (int fj = 0; fj < 4; ++fj)
#pragma unroll
            for (int reg = 0; reg < 4; ++reg) {
                const int rl = wr_ * (32 / WM) + fi * 16 + ((lane >> 4) << 2) + reg;
                const int cl = wc * 64 + fj * 16 + (lane & 15);
                float v = acc[fi][fj][reg] * inv[fi][reg];
                if constexpr (MODE == 2) {
                    outf[(size_t)(i0 + rl) * 256 + cl] = fmaxf(v, 0.f);
                } else {
                    const unsigned short u = f2bf(v);
                    xdst[(size_t)(i0 + rl) * DOUT + cl] = u;
                    if constexpr (DNEXT > 0) {
                        if (head) {
                            const int off = ((rl * DOUT + cl) * 2) ^ ((rl & 7) << 4);
                            *reinterpret_cast<unsigned short*>((char*)xbuf + off) = u;
                        }
                    }
                }
            }

    if constexpr (DNEXT > 0) {
        if (head) {
            __syncthreads();
            f32x4 acc2[DNEXT / 128][4];
            gemm_direct<DOUT, DNEXT, 2, false>(xbuf, Wnext, acc2, t);
            constexpr int WN2 = DNEXT / 64, WM2 = 4 / WN2, FM2 = DNEXT / 128;
            const int wr2 = wv / WN2, wc2 = wv % WN2;
#pragma unroll
            for (int fi = 0; fi < FM2; ++fi)
#pragma unroll
                for (int fj = 0; fj < 4; ++fj) {
                    const int rl0 = wr2 * (32 / WM2) + fi * 16 + ((lane >> 4) << 2);
                    const int cl  = wc2 * 64 + fj * 16 + (lane & 15);
                    ushort4 y;
                    y.x = f2bf(acc2[fi][fj][0]); y.y = f2bf(acc2[fi][fj][1]);
                    y.z = f2bf(acc2[fi][fj][2]); y.w = f2bf(acc2[fi][fj][3]);
                    *reinterpret_cast<ushort4*>(
                        YTnext + (size_t)cl * KROWS + i0 + rl0) = y;
                }
        }
    }
}

extern "C" void kernel_launch(void* const* d_in, const int* in_sizes, int n_in,
                              void* d_out, int out_size, void* d_ws, size_t ws_size,
                              hipStream_t stream)
{
    const float* flow = (const float*)d_in[0];
    const float* wl1 = (const float*)d_in[1];
    const float* bl1 = (const float*)d_in[2];
    const float* wr1 = (const float*)d_in[3];
    const float* wl2 = (const float*)d_in[4];
    const float* bl2 = (const float*)d_in[5];
    const float* wr2 = (const float*)d_in[6];
    const float* wl3 = (const float*)d_in[7];
    const float* bl3 = (const float*)d_in[8];
    const float* wr3 = (const float*)d_in[9];
    const float* wl4 = (const float*)d_in[10];
    const float* bl4 = (const float*)d_in[11];
    const float* wr4 = (const float*)d_in[12];
    float* out = (float*)d_out;

    char* p = (char*)d_ws;
    unsigned short* wbf = (unsigned short*)p;  p += 1 << 20;   // 327680 bf16 used
    unsigned short* x1  = (unsigned short*)p;  p += (size_t)NROWS * 128 * 2;
    unsigned short* x2  = (unsigned short*)p;  p += (size_t)NROWS * 256 * 2;
    unsigned short* x3  = (unsigned short*)p;  p += (size_t)NROWS * 128 * 2;
    unsigned short* YT1 = (unsigned short*)p;  p += (size_t)128 * KROWS * 2;
    unsigned short* YT2 = (unsigned short*)p;  p += (size_t)256 * KROWS * 2;
    unsigned short* YT3 = (unsigned short*)p;  p += (size_t)128 * KROWS * 2;
    unsigned short* YT4 = (unsigned short*)p;

    const unsigned short* wr1b = wbf;
    const unsigned short* wl2b = wbf + 131072;
    const unsigned short* wr2b = wbf + 163840;
    const unsigned short* wl3b = wbf + 196608;
    const unsigned short* wr3b = wbf + 229376;
    const unsigned short* wl4b = wbf + 262144;
    const unsigned short* wr4b = wbf + 294912;

    // D1: weight cvt + proj1 (+ tuple scalar)
    prep_kernel<<<352, 256, 0, stream>>>(flow, wl1, wr1, wl2, wr2, wl3, wr3,
                                         wl4, wr4, wbf, YT1,
                                         out + (size_t)NROWS * 256);
    // D2: L1  din=1024 dout=128 (fp32 A), heads emit YT2
    main_kernel<1024, 128, 256, true , 1><<<1024, 256, 0, stream>>>(
        flow, wr1b, bl1, YT1, wl2b, x1, nullptr, YT2);
    // D3: L2  din=128 dout=256, heads emit YT3
    main_kernel< 128, 256, 128, false, 1><<<1024, 256, 0, stream>>>(
        x1, wr2b, bl2, YT2, wl3b, x2, nullptr, YT3);
    // D4: L3  din=256 dout=128, heads emit YT4
    main_kernel< 256, 128, 256, false, 1><<<1024, 256, 0, stream>>>(
        x2, wr3b, bl3, YT3, wl4b, x3, nullptr, YT4);
    // D5: L4  din=128 dout=256 + relu -> fp32 out
    main_kernel< 128, 256,   0, false, 2><<<1024, 256, 0, stream>>>(
        x3, wr4b, bl4, YT4, nullptr, nullptr, out, nullptr);
}

// Round 8
// 201.467 us; speedup vs baseline: 1.3791x; 1.3791x over previous
//
#include <hip/hip_runtime.h>
#include <math.h>

// ---------------------------------------------------------------------------
// Encoder_Flows on MI355X — 5 dispatches, R5-proven staged-LDS GEMM cores.
//   prep  : weight fp32->bf16 cvt + proj1 (YT1 = (flow[:1024]@wl1^T)^T) + scalar
//   main_L: 1024 blocks x 32 rows, staged coalesced LDS GEMM (R5 core):
//           [head<32: staged scan-GEMM agg from YT_L] + X@wr^T + bias(+agg)
//           + row-L2-norm -> x_L bf16 (L4: relu -> fp32 out).
//           Head blocks then reuse dead Abuf/Bbuf LDS as swizzled xbuf and
//           run next layer's proj (A from LDS, B L2-resident) -> YT_{L+1}.
// Lessons: R7 direct-frag global loads (uncoalesced) = 10x slower; R6 serial
// in-block layer chain = latency-bound. Keep R5 cores, cut dispatches 9->5.
// ---------------------------------------------------------------------------

typedef __attribute__((ext_vector_type(8))) short short8;
typedef __attribute__((ext_vector_type(4))) float f32x4;

constexpr int NROWS = 32768;
constexpr int KROWS = 1024;

static __device__ __forceinline__ unsigned short f2bf(float f) {
    unsigned int u = __float_as_uint(f);
    return (unsigned short)((u + 0x7fffu + ((u >> 16) & 1u)) >> 16);
}

// ---- coalesced reg-staging helpers (tile ROWS x 64 -> XOR-swizzled LDS) ---
template<int ROWS>
struct RegsBF {
    short8 v[ROWS / 32];
    __device__ __forceinline__ void load(const unsigned short* src, int ld,
                                         int k0, int t) {
#pragma unroll
        for (int j = 0; j < ROWS / 32; ++j) {
            int idx = j * 256 + t; int r = idx >> 3, f = idx & 7;
            v[j] = *reinterpret_cast<const short8*>(
                src + (size_t)r * ld + k0 + f * 8);
        }
    }
    __device__ __forceinline__ void store(unsigned short* buf, int t) {
#pragma unroll
        for (int j = 0; j < ROWS / 32; ++j) {
            int idx = j * 256 + t; int r = idx >> 3, f = idx & 7;
            int off = (r * 128 + f * 16) ^ ((r & 7) << 4);
            *reinterpret_cast<short8*>((char*)buf + off) = v[j];
        }
    }
};

template<int ROWS>
struct RegsF32 {
    float4 v[ROWS / 16];
    __device__ __forceinline__ void load(const float* src, int ld,
                                         int k0, int t) {
#pragma unroll
        for (int j = 0; j < ROWS / 32; ++j) {
            int idx = j * 256 + t; int r = idx >> 3, f = idx & 7;
            const float* p = src + (size_t)r * ld + k0 + f * 8;
            v[2 * j]     = *reinterpret_cast<const float4*>(p);
            v[2 * j + 1] = *reinterpret_cast<const float4*>(p + 4);
        }
    }
    __device__ __forceinline__ void store(unsigned short* buf, int t) {
#pragma unroll
        for (int j = 0; j < ROWS / 32; ++j) {
            int idx = j * 256 + t; int r = idx >> 3, f = idx & 7;
            float4 a = v[2 * j], b = v[2 * j + 1];
            short8 s;
            s[0] = (short)f2bf(a.x); s[1] = (short)f2bf(a.y);
            s[2] = (short)f2bf(a.z); s[3] = (short)f2bf(a.w);
            s[4] = (short)f2bf(b.x); s[5] = (short)f2bf(b.y);
            s[6] = (short)f2bf(b.z); s[7] = (short)f2bf(b.w);
            int off = (r * 128 + f * 16) ^ ((r & 7) << 4);
            *reinterpret_cast<short8*>((char*)buf + off) = s;
        }
    }
};

// ---- staged 32xDIN @ (DOUT x DIN)^T GEMM (R5 core; 2 barriers per k-step) --
template<int DIN, int DOUT, bool AFP32, bool BFP32>
__device__ __forceinline__ void staged_gemm(const void* __restrict__ Av,
    const void* __restrict__ Wv, f32x4 (&acc)[DOUT / 128][4],
    unsigned short* Abuf, unsigned short* Bbuf, int t)
{
    constexpr int WN = DOUT / 64, WM = 4 / WN, FM = DOUT / 128, NT = DIN / 64;
    const int wv = t >> 6, lane = t & 63, wr_ = wv / WN, wc = wv % WN;
#pragma unroll
    for (int fi = 0; fi < FM; ++fi)
#pragma unroll
        for (int fj = 0; fj < 4; ++fj) acc[fi][fj] = (f32x4){0.f, 0.f, 0.f, 0.f};

    RegsF32<32>  arf; RegsBF<32>  arb;
    RegsF32<DOUT> brf; RegsBF<DOUT> brb;
    if (AFP32) arf.load((const float*)Av, DIN, 0, t);
    else       arb.load((const unsigned short*)Av, DIN, 0, t);
    if (BFP32) brf.load((const float*)Wv, DIN, 0, t);
    else       brb.load((const unsigned short*)Wv, DIN, 0, t);

    for (int kt = 0; kt < NT; ++kt) {
        if (kt) __syncthreads();
        if (AFP32) arf.store(Abuf, t); else arb.store(Abuf, t);
        if (BFP32) brf.store(Bbuf, t); else brb.store(Bbuf, t);
        __syncthreads();
        if (kt + 1 < NT) {
            const int kn = (kt + 1) * 64;
            if (AFP32) arf.load((const float*)Av, DIN, kn, t);
            else       arb.load((const unsigned short*)Av, DIN, kn, t);
            if (BFP32) brf.load((const float*)Wv, DIN, kn, t);
            else       brb.load((const unsigned short*)Wv, DIN, kn, t);
        }
#pragma unroll
        for (int kk = 0; kk < 2; ++kk) {
            short8 a[FM], b[4];
#pragma unroll
            for (int fi = 0; fi < FM; ++fi) {
                const int rA = wr_ * (32 / WM) + fi * 16 + (lane & 15);
                const int off = (rA * 128 + kk * 64 + (lane >> 4) * 16) ^ ((rA & 7) << 4);
                a[fi] = *reinterpret_cast<const short8*>((const char*)Abuf + off);
            }
#pragma unroll
            for (int fj = 0; fj < 4; ++fj) {
                const int rB = wc * 64 + fj * 16 + (lane & 15);
                const int off = (rB * 128 + kk * 64 + (lane >> 4) * 16) ^ ((rB & 7) << 4);
                b[fj] = *reinterpret_cast<const short8*>((const char*)Bbuf + off);
            }
#pragma unroll
            for (int fi = 0; fi < FM; ++fi)
#pragma unroll
                for (int fj = 0; fj < 4; ++fj)
                    acc[fi][fj] = __builtin_amdgcn_mfma_f32_16x16x32_bf16(
                        a[fi], b[fj], acc[fi][fj], 0, 0, 0);
        }
    }
}

// ---- staged scan-GEMM (R5): agg = (L @ Y)/cnt from Y^T (DOUT x 1024) ------
template<int DOUT>
__device__ __forceinline__ void scan_staged(const unsigned short* __restrict__ YT,
    int i0, f32x4 (&agg)[DOUT / 128][4], unsigned short* Bbuf, int t)
{
    constexpr int WN = DOUT / 64, WM = 4 / WN, FM = DOUT / 128;
    const int wv = t >> 6, lane = t & 63, wr_ = wv / WN, wc = wv % WN;
#pragma unroll
    for (int fi = 0; fi < FM; ++fi)
#pragma unroll
        for (int fj = 0; fj < 4; ++fj) agg[fi][fj] = (f32x4){0.f, 0.f, 0.f, 0.f};
    const int nt2 = (i0 + 95) >> 6;             // ceil((i0+32)/64)
    RegsBF<DOUT> sb;
    sb.load(YT, KROWS, 0, t);
    for (int kt = 0; kt < nt2; ++kt) {
        if (kt) __syncthreads();
        sb.store(Bbuf, t);
        __syncthreads();
        if (kt + 1 < nt2) sb.load(YT, KROWS, (kt + 1) * 64, t);
#pragma unroll
        for (int kk = 0; kk < 2; ++kk) {
            const int jb = kt * 64 + kk * 32 + ((lane >> 4) << 3);
            short8 a[FM], b[4];
#pragma unroll
            for (int fi = 0; fi < FM; ++fi) {
                const int irow = i0 + wr_ * (32 / WM) + fi * 16 + (lane & 15);
#pragma unroll
                for (int e = 0; e < 8; ++e)
                    a[fi][e] = (short)((jb + e < irow) ? 0x3F80 : 0);
            }
#pragma unroll
            for (int fj = 0; fj < 4; ++fj) {
                const int rB = wc * 64 + fj * 16 + (lane & 15);
                const int off = (rB * 128 + kk * 64 + (lane >> 4) * 16) ^ ((rB & 7) << 4);
                b[fj] = *reinterpret_cast<const short8*>((const char*)Bbuf + off);
            }
#pragma unroll
            for (int fi = 0; fi < FM; ++fi)
#pragma unroll
                for (int fj = 0; fj < 4; ++fj)
                    agg[fi][fj] = __builtin_amdgcn_mfma_f32_16x16x32_bf16(
                        a[fi], b[fj], agg[fi][fj], 0, 0, 0);
        }
    }
#pragma unroll
    for (int fi = 0; fi < FM; ++fi)
#pragma unroll
        for (int reg = 0; reg < 4; ++reg) {
            const int i_abs = i0 + wr_ * (32 / WM) + fi * 16 + ((lane >> 4) << 2) + reg;
            const float inv = 1.0f / (float)(i_abs > 1 ? i_abs : 1);
#pragma unroll
            for (int fj = 0; fj < 4; ++fj) agg[fi][fj][reg] *= inv;
        }
    __syncthreads();                            // free Bbuf for bulk GEMM
}

// ---- small proj GEMM: A from swizzled LDS xbuf, B direct from global ------
template<int DIN, int DOUT>
__device__ __forceinline__ void proj_lds(const unsigned short* __restrict__ xbuf,
    const unsigned short* __restrict__ W, f32x4 (&acc)[DOUT / 128][4], int t)
{
    constexpr int WN = DOUT / 64, WM = 4 / WN, FM = DOUT / 128;
    const int wv = t >> 6, lane = t & 63, wr_ = wv / WN, wc = wv % WN;
#pragma unroll
    for (int fi = 0; fi < FM; ++fi)
#pragma unroll
        for (int fj = 0; fj < 4; ++fj) acc[fi][fj] = (f32x4){0.f, 0.f, 0.f, 0.f};
#pragma unroll
    for (int kt = 0; kt < DIN / 32; ++kt) {
        const int k0 = kt * 32 + ((lane >> 4) << 3);
        short8 a[FM], b[4];
#pragma unroll
        for (int fi = 0; fi < FM; ++fi) {
            const int rA = wr_ * (32 / WM) + fi * 16 + (lane & 15);
            const int off = ((rA * DIN + k0) * 2) ^ ((rA & 7) << 4);
            a[fi] = *reinterpret_cast<const short8*>((const char*)xbuf + off);
        }
#pragma unroll
        for (int fj = 0; fj < 4; ++fj) {
            const int o = wc * 64 + fj * 16 + (lane & 15);
            b[fj] = *reinterpret_cast<const short8*>(W + (size_t)o * DIN + k0);
        }
#pragma unroll
        for (int fi = 0; fi < FM; ++fi)
#pragma unroll
            for (int fj = 0; fj < 4; ++fj)
                acc[fi][fj] = __builtin_amdgcn_mfma_f32_16x16x32_bf16(
                    a[fi], b[fj], acc[fi][fj], 0, 0, 0);
    }
}

// ---- bias(+agg) add + row L2-norm across block ----------------------------
template<int DOUT>
__device__ __forceinline__ void norm_rows(f32x4 (&acc)[DOUT / 128][4],
    const float* __restrict__ bias, const f32x4 (*agg)[4],
    float* ssred, int t, float (&inv)[DOUT / 128][4])
{
    constexpr int WN = DOUT / 64, WM = 4 / WN, FM = DOUT / 128;
    const int wv = t >> 6, lane = t & 63, wr_ = wv / WN, wc = wv % WN;
    float bb[4];
#pragma unroll
    for (int fj = 0; fj < 4; ++fj) bb[fj] = bias[wc * 64 + fj * 16 + (lane & 15)];
#pragma unroll
    for (int fi = 0; fi < FM; ++fi)
#pragma unroll
        for (int fj = 0; fj < 4; ++fj)
#pragma unroll
            for (int reg = 0; reg < 4; ++reg) {
                float v = acc[fi][fj][reg] + bb[fj];
                if (agg) v += agg[fi][fj][reg];
                acc[fi][fj][reg] = v;
            }
#pragma unroll
    for (int fi = 0; fi < FM; ++fi)
#pragma unroll
        for (int reg = 0; reg < 4; ++reg) {
            float s = 0.f;
#pragma unroll
            for (int fj = 0; fj < 4; ++fj) { float v = acc[fi][fj][reg]; s += v * v; }
#pragma unroll
            for (int m = 8; m >= 1; m >>= 1) s += __shfl_xor(s, m);
            if ((lane & 15) == 0) {
                const int rl = wr_ * (32 / WM) + fi * 16 + ((lane >> 4) << 2) + reg;
                ssred[wc * 32 + rl] = s;
            }
        }
    __syncthreads();
#pragma unroll
    for (int fi = 0; fi < FM; ++fi)
#pragma unroll
        for (int reg = 0; reg < 4; ++reg) {
            const int rl = wr_ * (32 / WM) + fi * 16 + ((lane >> 4) << 2) + reg;
            float s = 0.f;
#pragma unroll
            for (int c = 0; c < WN; ++c) s += ssred[c * 32 + rl];
            inv[fi][reg] = 1.0f / fmaxf(sqrtf(s), 1e-12f);
        }
}

// ---------------------------------------------------------------------------
// prep: blocks [0,32) proj1 staged -> YT1; blocks [32,352) weight cvt; scalar.
// ---------------------------------------------------------------------------
__global__ __launch_bounds__(256, 2)
void prep_kernel(const float* __restrict__ flow, const float* __restrict__ wl1,
                 const float* __restrict__ wr1, const float* __restrict__ wl2,
                 const float* __restrict__ wr2, const float* __restrict__ wl3,
                 const float* __restrict__ wr3, const float* __restrict__ wl4,
                 const float* __restrict__ wr4,
                 unsigned short* __restrict__ wbf,
                 unsigned short* __restrict__ YT1, float* __restrict__ outscalar)
{
    __shared__ unsigned short Abuf[32 * 64];
    __shared__ unsigned short Bbuf[128 * 64];
    const int t = threadIdx.x, bid = blockIdx.x;
    if (bid >= 32) {
        if (bid == 32 && t == 0) outscalar[0] = 1.0f;
        int g = (bid - 32) * 1024 + t * 4;
        const float* src; int off;
        if      (g < 131072) { src = wr1; off = g; }
        else if (g < 163840) { src = wl2; off = g - 131072; }
        else if (g < 196608) { src = wr2; off = g - 163840; }
        else if (g < 229376) { src = wl3; off = g - 196608; }
        else if (g < 262144) { src = wr3; off = g - 229376; }
        else if (g < 294912) { src = wl4; off = g - 262144; }
        else                 { src = wr4; off = g - 294912; }
        float4 v = *reinterpret_cast<const float4*>(src + off);
        ushort4 o4;
        o4.x = f2bf(v.x); o4.y = f2bf(v.y); o4.z = f2bf(v.z); o4.w = f2bf(v.w);
        *reinterpret_cast<ushort4*>(wbf + g) = o4;
        return;
    }
    const int i0 = bid * 32, wv = t >> 6, lane = t & 63;
    const int wr_ = wv >> 1, wc = wv & 1;       // DOUT=128 mapping
    f32x4 acc[1][4];
    staged_gemm<1024, 128, true, true>(flow + (size_t)i0 * 1024, wl1,
                                       acc, Abuf, Bbuf, t);
#pragma unroll
    for (int fj = 0; fj < 4; ++fj) {
        const int rl0 = wr_ * 16 + ((lane >> 4) << 2);
        const int cl  = wc * 64 + fj * 16 + (lane & 15);
        ushort4 y;
        y.x = f2bf(acc[0][fj][0]); y.y = f2bf(acc[0][fj][1]);
        y.z = f2bf(acc[0][fj][2]); y.w = f2bf(acc[0][fj][3]);
        *reinterpret_cast<ushort4*>(YT1 + (size_t)cl * KROWS + i0 + rl0) = y;
    }
}

// ---------------------------------------------------------------------------
// main_L: 1024 blocks x 32 rows, staged GEMM; heads add scan-agg + next proj.
// ---------------------------------------------------------------------------
template<int DIN, int DOUT, int DNEXT, bool AFP32, int MODE, int MINW>
__global__ __launch_bounds__(256, MINW)
void main_kernel(const void* __restrict__ Xv,
    const unsigned short* __restrict__ W, const float* __restrict__ bias,
    const unsigned short* __restrict__ YT,
    const unsigned short* __restrict__ Wnext,
    unsigned short* __restrict__ xdst, float* __restrict__ outf,
    unsigned short* __restrict__ YTnext)
{
    constexpr int WN = DOUT / 64, WM = 4 / WN, FM = DOUT / 128;
    __shared__ char smem[4096 + DOUT * 128];    // Abuf(4KB) + Bbuf(DOUT*64*2B)
    __shared__ float ssred[128];
    unsigned short* Abuf = (unsigned short*)smem;
    unsigned short* Bbuf = (unsigned short*)(smem + 4096);
    unsigned short* xbuf = (unsigned short*)smem;   // reused after GEMM (head)

    const int t = threadIdx.x, wv = t >> 6, lane = t & 63;
    const int wr_ = wv / WN, wc = wv % WN;
    const int i0 = blockIdx.x * 32;
    const bool head = (i0 < KROWS);             // block-uniform

    f32x4 agg[FM][4];
    if (head) scan_staged<DOUT>(YT, i0, agg, Bbuf, t);

    f32x4 acc[FM][4];
    if constexpr (AFP32)
        staged_gemm<DIN, DOUT, true , false>(
            (const float*)Xv + (size_t)i0 * DIN, W, acc, Abuf, Bbuf, t);
    else
        staged_gemm<DIN, DOUT, false, false>(
            (const unsigned short*)Xv + (size_t)i0 * DIN, W, acc, Abuf, Bbuf, t);

    float inv[FM][4];
    norm_rows<DOUT>(acc, bias, head ? &agg[0] : nullptr, ssred, t, inv);

#pragma unroll
    for (int fi = 0; fi < FM; ++fi)
#pragma unroll
        for (int fj = 0; fj < 4; ++fj)
#pragma unroll
            for (int reg = 0; reg < 4; ++reg) {
                const int rl = wr_ * (32 / WM) + fi * 16 + ((lane >> 4) << 2) + reg;
                const int cl = wc * 64 + fj * 16 + (lane & 15);
                float v = acc[fi][fj][reg] * inv[fi][reg];
                if constexpr (MODE == 2) {
                    outf[(size_t)(i0 + rl) * 256 + cl] = fmaxf(v, 0.f);
                } else {
                    const unsigned short u = f2bf(v);
                    xdst[(size_t)(i0 + rl) * DOUT + cl] = u;
                    if constexpr (DNEXT > 0) {
                        if (head) {
                            const int off = ((rl * DOUT + cl) * 2) ^ ((rl & 7) << 4);
                            *reinterpret_cast<unsigned short*>((char*)xbuf + off) = u;
                        }
                    }
                }
            }

    if constexpr (DNEXT > 0) {
        if (head) {
            __syncthreads();                    // xbuf writes visible
            f32x4 acc2[DNEXT / 128][4];
            proj_lds<DOUT, DNEXT>(xbuf, Wnext, acc2, t);
            constexpr int WN2 = DNEXT / 64, WM2 = 4 / WN2, FM2 = DNEXT / 128;
            const int wr2 = wv / WN2, wc2 = wv % WN2;
#pragma unroll
            for (int fi = 0; fi < FM2; ++fi)
#pragma unroll
                for (int fj = 0; fj < 4; ++fj) {
                    const int rl0 = wr2 * (32 / WM2) + fi * 16 + ((lane >> 4) << 2);
                    const int cl  = wc2 * 64 + fj * 16 + (lane & 15);
                    ushort4 y;
                    y.x = f2bf(acc2[fi][fj][0]); y.y = f2bf(acc2[fi][fj][1]);
                    y.z = f2bf(acc2[fi][fj][2]); y.w = f2bf(acc2[fi][fj][3]);
                    *reinterpret_cast<ushort4*>(
                        YTnext + (size_t)cl * KROWS + i0 + rl0) = y;
                }
        }
    }
}

extern "C" void kernel_launch(void* const* d_in, const int* in_sizes, int n_in,
                              void* d_out, int out_size, void* d_ws, size_t ws_size,
                              hipStream_t stream)
{
    const float* flow = (const float*)d_in[0];
    const float* wl1 = (const float*)d_in[1];
    const float* bl1 = (const float*)d_in[2];
    const float* wr1 = (const float*)d_in[3];
    const float* wl2 = (const float*)d_in[4];
    const float* bl2 = (const float*)d_in[5];
    const float* wr2 = (const float*)d_in[6];
    const float* wl3 = (const float*)d_in[7];
    const float* bl3 = (const float*)d_in[8];
    const float* wr3 = (const float*)d_in[9];
    const float* wl4 = (const float*)d_in[10];
    const float* bl4 = (const float*)d_in[11];
    const float* wr4 = (const float*)d_in[12];
    float* out = (float*)d_out;

    char* p = (char*)d_ws;
    unsigned short* wbf = (unsigned short*)p;  p += 1 << 20;   // 327680 bf16 used
    unsigned short* x1  = (unsigned short*)p;  p += (size_t)NROWS * 128 * 2;
    unsigned short* x2  = (unsigned short*)p;  p += (size_t)NROWS * 256 * 2;
    unsigned short* x3  = (unsigned short*)p;  p += (size_t)NROWS * 128 * 2;
    unsigned short* YT1 = (unsigned short*)p;  p += (size_t)128 * KROWS * 2;
    unsigned short* YT2 = (unsigned short*)p;  p += (size_t)256 * KROWS * 2;
    unsigned short* YT3 = (unsigned short*)p;  p += (size_t)128 * KROWS * 2;
    unsigned short* YT4 = (unsigned short*)p;

    const unsigned short* wr1b = wbf;
    const unsigned short* wl2b = wbf + 131072;
    const unsigned short* wr2b = wbf + 163840;
    const unsigned short* wl3b = wbf + 196608;
    const unsigned short* wr3b = wbf + 229376;
    const unsigned short* wl4b = wbf + 262144;
    const unsigned short* wr4b = wbf + 294912;

    // D1: weight cvt + proj1 (+ tuple scalar)
    prep_kernel<<<352, 256, 0, stream>>>(flow, wl1, wr1, wl2, wr2, wl3, wr3,
                                         wl4, wr4, wbf, YT1,
                                         out + (size_t)NROWS * 256);
    // D2: L1  din=1024 dout=128 (fp32 A), heads emit YT2
    main_kernel<1024, 128, 256, true , 1, 4><<<1024, 256, 0, stream>>>(
        flow, wr1b, bl1, YT1, wl2b, x1, nullptr, YT2);
    // D3: L2  din=128 dout=256, heads emit YT3
    main_kernel< 128, 256, 128, false, 1, 3><<<1024, 256, 0, stream>>>(
        x1, wr2b, bl2, YT2, wl3b, x2, nullptr, YT3);
    // D4: L3  din=256 dout=128, heads emit YT4
    main_kernel< 256, 128, 256, false, 1, 4><<<1024, 256, 0, stream>>>(
        x2, wr3b, bl3, YT3, wl4b, x3, nullptr, YT4);
    // D5: L4  din=128 dout=256 + relu -> fp32 out
    main_kernel< 128, 256,   0, false, 2, 3><<<1024, 256, 0, stream>>>(
        x3, wr4b, bl4, YT4, nullptr, nullptr, out, nullptr);
}

// Round 9
// 200.074 us; speedup vs baseline: 1.3887x; 1.0070x over previous
//
#include <hip/hip_runtime.h>
#include <math.h>

// ---------------------------------------------------------------------------
// Encoder_Flows on MI355X — 9 dispatches (R5-proven structure) + split-K projs.
// Per layer: proj (split-K, fp32 transposed partial slabs Yp[sp][o][j])
//            -> main (1024x32-row blocks: staged GEMM + head scan-GEMM agg
//               [stage = sum KS fp32 slabs -> bf16 swizzled LDS] + bias
//               + row-L2-norm -> bf16 x  [L4: relu -> fp32 out]).
// agg@w_l^T = (L @ Y)/cnt, L = strictly-lower-triangular ones (exact bf16).
// Lessons: R6/R7/R8 fusions all regressed vs this chain — keep dispatches
// simple; shrink proj serial latency via split-K instead.
// ---------------------------------------------------------------------------

typedef __attribute__((ext_vector_type(8))) short short8;
typedef __attribute__((ext_vector_type(4))) float f32x4;

constexpr int NROWS = 32768;
constexpr int KROWS = 1024;

static __device__ __forceinline__ unsigned short f2bf(float f) {
    unsigned int u = __float_as_uint(f);
    return (unsigned short)((u + 0x7fffu + ((u >> 16) & 1u)) >> 16);
}

// ---- weight fp32->bf16 conversion (+ tuple scalar write) ------------------
__global__ __launch_bounds__(256)
void cvt_weights(const float* __restrict__ wl1, const float* __restrict__ wr1,
                 const float* __restrict__ wl2, const float* __restrict__ wr2,
                 const float* __restrict__ wl3, const float* __restrict__ wr3,
                 const float* __restrict__ wl4, const float* __restrict__ wr4,
                 unsigned short* __restrict__ dst, float* __restrict__ outscalar)
{
    if (blockIdx.x == 0 && threadIdx.x == 0) outscalar[0] = 1.0f;
    int g = (blockIdx.x * 256 + threadIdx.x) * 4;
    const float* src; int off;
    if      (g < 131072) { src = wl1; off = g; }
    else if (g < 262144) { src = wr1; off = g - 131072; }
    else if (g < 294912) { src = wl2; off = g - 262144; }
    else if (g < 327680) { src = wr2; off = g - 294912; }
    else if (g < 360448) { src = wl3; off = g - 327680; }
    else if (g < 393216) { src = wr3; off = g - 360448; }
    else if (g < 425984) { src = wl4; off = g - 393216; }
    else                 { src = wr4; off = g - 425984; }
    float4 v = *reinterpret_cast<const float4*>(src + off);
    ushort4 o;
    o.x = f2bf(v.x); o.y = f2bf(v.y); o.z = f2bf(v.z); o.w = f2bf(v.w);
    *reinterpret_cast<ushort4*>(dst + g) = o;
}

// ---- register staging helpers (tile ROWS x 64, XOR-swizzled LDS) ----------
template<int ROWS>
struct RegsBF {
    short8 v[ROWS / 32];
    __device__ __forceinline__ void load(const unsigned short* src, int ld,
                                         int r0, int k0, int t) {
#pragma unroll
        for (int j = 0; j < ROWS / 32; ++j) {
            int idx = j * 256 + t; int r = idx >> 3, f = idx & 7;
            v[j] = *reinterpret_cast<const short8*>(
                src + (size_t)(r0 + r) * ld + k0 + f * 8);
        }
    }
    __device__ __forceinline__ void store(unsigned short* buf, int t) {
#pragma unroll
        for (int j = 0; j < ROWS / 32; ++j) {
            int idx = j * 256 + t; int r = idx >> 3, f = idx & 7;
            int off = (r * 128 + f * 16) ^ ((r & 7) << 4);
            *reinterpret_cast<short8*>((char*)buf + off) = v[j];
        }
    }
};

template<int ROWS>
struct RegsF32 {
    float4 v[ROWS / 16];
    __device__ __forceinline__ void load(const float* src, int ld,
                                         int r0, int k0, int t) {
#pragma unroll
        for (int j = 0; j < ROWS / 32; ++j) {
            int idx = j * 256 + t; int r = idx >> 3, f = idx & 7;
            const float* p = src + (size_t)(r0 + r) * ld + k0 + f * 8;
            v[2 * j]     = *reinterpret_cast<const float4*>(p);
            v[2 * j + 1] = *reinterpret_cast<const float4*>(p + 4);
        }
    }
    __device__ __forceinline__ void store(unsigned short* buf, int t) {
#pragma unroll
        for (int j = 0; j < ROWS / 32; ++j) {
            int idx = j * 256 + t; int r = idx >> 3, f = idx & 7;
            float4 a = v[2 * j], b = v[2 * j + 1];
            short8 s;
            s[0] = (short)f2bf(a.x); s[1] = (short)f2bf(a.y);
            s[2] = (short)f2bf(a.z); s[3] = (short)f2bf(a.w);
            s[4] = (short)f2bf(b.x); s[5] = (short)f2bf(b.y);
            s[6] = (short)f2bf(b.z); s[7] = (short)f2bf(b.w);
            int off = (r * 128 + f * 16) ^ ((r & 7) << 4);
            *reinterpret_cast<short8*>((char*)buf + off) = s;
        }
    }
};

// ---------------------------------------------------------------------------
// MFMA GEMM.  out[i][o] = sum_k X[i][k]*W[o][k]  (+ epilogue)
//   MODE 0: proj partial slab -> Yp[blockIdx.y][o][j] fp32 (transposed)
//   MODE 1: scan-GEMM(agg from KS fp32 slabs) + bias + agg + L2-norm -> bf16
//   MODE 2: MODE1 + relu -> fp32 out
// ---------------------------------------------------------------------------
template<int DOUT, int BM, int WM, int WN, int MODE, bool AFP32, int KS, int MINW>
__global__ __launch_bounds__(256, MINW)
void mfma_gemm(const void* __restrict__ Xv,
               const unsigned short* __restrict__ W,
               const float* __restrict__ bias,
               float* __restrict__ Yp,            // KS x (DOUT x 1024) fp32
               float* __restrict__ outf,
               unsigned short* __restrict__ outb,
               int din, int kchunk)
{
    constexpr int BN = WN * 64;
    static_assert(BN == DOUT, "block must own full output rows");
    constexpr int FM = BM / (WM * 16);
    __shared__ unsigned short Abuf[BM * 64];
    __shared__ unsigned short Bbuf[BN * 64];
    __shared__ float ssred[WN * BM];

    const int t = threadIdx.x, wvid = t >> 6, lane = t & 63;
    const int wr_ = wvid / WN, wc = wvid % WN;
    const int i0 = blockIdx.x * BM;
    const int kb = (MODE == 0) ? blockIdx.y * kchunk : 0;
    const int nt = ((MODE == 0) ? kchunk : din) >> 6;
    const bool hasagg = (MODE != 0) && (i0 < KROWS);

    // ---- agg via scan-GEMM: agg = (L @ Y)/cnt; Y^T staged from KS slabs ----
    f32x4 agg[FM][4];
#pragma unroll
    for (int fi = 0; fi < FM; ++fi)
#pragma unroll
        for (int fj = 0; fj < 4; ++fj) agg[fi][fj] = (f32x4){0.f, 0.f, 0.f, 0.f};

    if (hasagg) {
        const int nt2 = (i0 + BM + 63) >> 6;    // rows only need j < i
        for (int kt = 0; kt < nt2; ++kt) {
            if (kt) __syncthreads();
            // stage: sum KS fp32 slabs of Y^T cols [kt*64, kt*64+64) -> bf16
#pragma unroll
            for (int j = 0; j < BN / 32; ++j) {
                int idx = j * 256 + t; int r = idx >> 3, f = idx & 7;
                const float* base = Yp + (size_t)r * KROWS + kt * 64 + f * 8;
                float4 s0 = *reinterpret_cast<const float4*>(base);
                float4 s1 = *reinterpret_cast<const float4*>(base + 4);
#pragma unroll
                for (int sp = 1; sp < KS; ++sp) {
                    const float* b2 = base + (size_t)sp * DOUT * KROWS;
                    float4 u0 = *reinterpret_cast<const float4*>(b2);
                    float4 u1 = *reinterpret_cast<const float4*>(b2 + 4);
                    s0.x += u0.x; s0.y += u0.y; s0.z += u0.z; s0.w += u0.w;
                    s1.x += u1.x; s1.y += u1.y; s1.z += u1.z; s1.w += u1.w;
                }
                short8 sv;
                sv[0] = (short)f2bf(s0.x); sv[1] = (short)f2bf(s0.y);
                sv[2] = (short)f2bf(s0.z); sv[3] = (short)f2bf(s0.w);
                sv[4] = (short)f2bf(s1.x); sv[5] = (short)f2bf(s1.y);
                sv[6] = (short)f2bf(s1.z); sv[7] = (short)f2bf(s1.w);
                int off = (r * 128 + f * 16) ^ ((r & 7) << 4);
                *reinterpret_cast<short8*>((char*)Bbuf + off) = sv;
            }
            __syncthreads();
#pragma unroll
            for (int kk = 0; kk < 2; ++kk) {
                const int jb = kt * 64 + kk * 32 + ((lane >> 4) << 3);
                short8 a[FM], b[4];
#pragma unroll
                for (int fi = 0; fi < FM; ++fi) {
                    const int irow = i0 + wr_ * (BM / WM) + fi * 16 + (lane & 15);
#pragma unroll
                    for (int e = 0; e < 8; ++e)
                        a[fi][e] = (short)((jb + e < irow) ? 0x3F80 : 0);
                }
#pragma unroll
                for (int fj = 0; fj < 4; ++fj) {
                    int rB = wc * 64 + fj * 16 + (lane & 15);
                    int off = (rB * 128 + kk * 64 + (lane >> 4) * 16) ^ ((rB & 7) << 4);
                    b[fj] = *reinterpret_cast<const short8*>((const char*)Bbuf + off);
                }
#pragma unroll
                for (int fi = 0; fi < FM; ++fi)
#pragma unroll
                    for (int fj = 0; fj < 4; ++fj)
                        agg[fi][fj] = __builtin_amdgcn_mfma_f32_16x16x32_bf16(
                            a[fi], b[fj], agg[fi][fj], 0, 0, 0);
            }
        }
        // divide by cnt = max(row, 1); C/D row = (lane>>4)*4 + reg
#pragma unroll
        for (int fi = 0; fi < FM; ++fi)
#pragma unroll
            for (int reg = 0; reg < 4; ++reg) {
                int i_abs = i0 + wr_ * (BM / WM) + fi * 16 + ((lane >> 4) << 2) + reg;
                float inv = 1.0f / (float)(i_abs > 1 ? i_abs : 1);
#pragma unroll
                for (int fj = 0; fj < 4; ++fj) agg[fi][fj][reg] *= inv;
            }
        __syncthreads();                        // Bbuf reads done before reuse
    }

    // ---- bulk GEMM (R5 core: coalesced reg staging + reg prefetch) --------
    f32x4 acc[FM][4];
#pragma unroll
    for (int fi = 0; fi < FM; ++fi)
#pragma unroll
        for (int fj = 0; fj < 4; ++fj) acc[fi][fj] = (f32x4){0.f, 0.f, 0.f, 0.f};

    RegsBF<BN> brg;
    RegsF32<BM> arf;
    RegsBF<BM> arb;
    if (AFP32) arf.load((const float*)Xv, din, i0, kb, t);
    else       arb.load((const unsigned short*)Xv, din, i0, kb, t);
    brg.load(W, din, 0, kb, t);

    for (int kt = 0; kt < nt; ++kt) {
        if (kt) __syncthreads();
        if (AFP32) arf.store(Abuf, t); else arb.store(Abuf, t);
        brg.store(Bbuf, t);
        __syncthreads();
        if (kt + 1 < nt) {
            int kn = kb + (kt + 1) * 64;
            if (AFP32) arf.load((const float*)Xv, din, i0, kn, t);
            else       arb.load((const unsigned short*)Xv, din, i0, kn, t);
            brg.load(W, din, 0, kn, t);
        }
#pragma unroll
        for (int kk = 0; kk < 2; ++kk) {
            short8 a[FM], b[4];
#pragma unroll
            for (int fi = 0; fi < FM; ++fi) {
                int rA = wr_ * (BM / WM) + fi * 16 + (lane & 15);
                int off = (rA * 128 + kk * 64 + (lane >> 4) * 16) ^ ((rA & 7) << 4);
                a[fi] = *reinterpret_cast<const short8*>((const char*)Abuf + off);
            }
#pragma unroll
            for (int fj = 0; fj < 4; ++fj) {
                int rB = wc * 64 + fj * 16 + (lane & 15);
                int off = (rB * 128 + kk * 64 + (lane >> 4) * 16) ^ ((rB & 7) << 4);
                b[fj] = *reinterpret_cast<const short8*>((const char*)Bbuf + off);
            }
#pragma unroll
            for (int fi = 0; fi < FM; ++fi)
#pragma unroll
                for (int fj = 0; fj < 4; ++fj)
                    acc[fi][fj] = __builtin_amdgcn_mfma_f32_16x16x32_bf16(
                        a[fi], b[fj], acc[fi][fj], 0, 0, 0);
        }
    }

    // C/D frag layout (m89): col = lane&15, row = (lane>>4)*4 + reg
    if (MODE == 0) {
        // transposed fp32 partial: Yp[slab][cl][i0+rl], float4 over 4 regs
        float* dst = Yp + (size_t)blockIdx.y * DOUT * KROWS;
#pragma unroll
        for (int fi = 0; fi < FM; ++fi)
#pragma unroll
            for (int fj = 0; fj < 4; ++fj) {
                int rl0 = wr_ * (BM / WM) + fi * 16 + ((lane >> 4) << 2);
                int cl  = wc * 64 + fj * 16 + (lane & 15);
                float4 y;
                y.x = acc[fi][fj][0]; y.y = acc[fi][fj][1];
                y.z = acc[fi][fj][2]; y.w = acc[fi][fj][3];
                *reinterpret_cast<float4*>(
                    dst + (size_t)cl * KROWS + i0 + rl0) = y;
            }
        return;
    }

    float bb[4];
#pragma unroll
    for (int fj = 0; fj < 4; ++fj) bb[fj] = bias[wc * 64 + fj * 16 + (lane & 15)];

#pragma unroll
    for (int fi = 0; fi < FM; ++fi)
#pragma unroll
        for (int fj = 0; fj < 4; ++fj)
#pragma unroll
            for (int reg = 0; reg < 4; ++reg)
                acc[fi][fj][reg] += bb[fj] + agg[fi][fj][reg];

    float sstot[FM][4];
#pragma unroll
    for (int fi = 0; fi < FM; ++fi)
#pragma unroll
        for (int reg = 0; reg < 4; ++reg) {
            float s = 0.f;
#pragma unroll
            for (int fj = 0; fj < 4; ++fj) {
                float v = acc[fi][fj][reg];
                s += v * v;
            }
#pragma unroll
            for (int m = 8; m >= 1; m >>= 1) s += __shfl_xor(s, m);
            if ((lane & 15) == 0) {
                int rl = wr_ * (BM / WM) + fi * 16 + ((lane >> 4) << 2) + reg;
                ssred[wc * BM + rl] = s;
            }
        }
    __syncthreads();
#pragma unroll
    for (int fi = 0; fi < FM; ++fi)
#pragma unroll
        for (int reg = 0; reg < 4; ++reg) {
            int rl = wr_ * (BM / WM) + fi * 16 + ((lane >> 4) << 2) + reg;
            float s = 0.f;
#pragma unroll
            for (int c = 0; c < WN; ++c) s += ssred[c * BM + rl];
            sstot[fi][reg] = 1.0f / fmaxf(sqrtf(s), 1e-12f);
        }

#pragma unroll
    for (int fi = 0; fi < FM; ++fi)
#pragma unroll
        for (int fj = 0; fj < 4; ++fj)
#pragma unroll
            for (int reg = 0; reg < 4; ++reg) {
                int rl = wr_ * (BM / WM) + fi * 16 + ((lane >> 4) << 2) + reg;
                int cl = wc * 64 + fj * 16 + (lane & 15);
                float v = acc[fi][fj][reg] * sstot[fi][reg];
                if (MODE == 2) {
                    v = fmaxf(v, 0.f);
                    outf[(size_t)(i0 + rl) * DOUT + cl] = v;
                } else {
                    outb[(size_t)(i0 + rl) * DOUT + cl] = f2bf(v);
                }
            }
}

extern "C" void kernel_launch(void* const* d_in, const int* in_sizes, int n_in,
                              void* d_out, int out_size, void* d_ws, size_t ws_size,
                              hipStream_t stream)
{
    const float* flow = (const float*)d_in[0];
    const float* wl1 = (const float*)d_in[1];
    const float* bl1 = (const float*)d_in[2];
    const float* wr1 = (const float*)d_in[3];
    const float* wl2 = (const float*)d_in[4];
    const float* bl2 = (const float*)d_in[5];
    const float* wr2 = (const float*)d_in[6];
    const float* wl3 = (const float*)d_in[7];
    const float* bl3 = (const float*)d_in[8];
    const float* wr3 = (const float*)d_in[9];
    const float* wl4 = (const float*)d_in[10];
    const float* bl4 = (const float*)d_in[11];
    const float* wr4 = (const float*)d_in[12];
    float* out = (float*)d_out;

    char* p = (char*)d_ws;
    unsigned short* wbf = (unsigned short*)p;  p += 1 << 20;
    unsigned short* xA  = (unsigned short*)p;  p += (size_t)NROWS * 128 * 2;
    unsigned short* xB  = (unsigned short*)p;  p += (size_t)NROWS * 256 * 2;
    float* Yp = (float*)p;                     p += (size_t)4 * 128 * KROWS * 4; // 2MB shared slabs

    const unsigned short* wl1b = wbf;
    const unsigned short* wr1b = wbf + 131072;
    const unsigned short* wl2b = wbf + 262144;
    const unsigned short* wr2b = wbf + 294912;
    const unsigned short* wl3b = wbf + 327680;
    const unsigned short* wr3b = wbf + 360448;
    const unsigned short* wl4b = wbf + 393216;
    const unsigned short* wr4b = wbf + 425984;

    cvt_weights<<<448, 256, 0, stream>>>(wl1, wr1, wl2, wr2, wl3, wr3, wl4, wr4,
                                         wbf, out + (size_t)NROWS * 256);

    // ---- L1: din=1024, dout=128, X = flow (fp32); proj split-K=4 ----
    mfma_gemm<128, 32, 2, 2, 0, true , 4, 2><<<dim3(32, 4), 256, 0, stream>>>(
        flow, wl1b, nullptr, Yp, nullptr, nullptr, 1024, 256);
    mfma_gemm<128, 32, 2, 2, 1, true , 4, 4><<<dim3(1024, 1), 256, 0, stream>>>(
        flow, wr1b, bl1, Yp, nullptr, xA, 1024, 0);

    // ---- L2: din=128, dout=256; proj split-K=2 ----
    mfma_gemm<256, 32, 1, 4, 0, false, 2, 2><<<dim3(32, 2), 256, 0, stream>>>(
        xA, wl2b, nullptr, Yp, nullptr, nullptr, 128, 64);
    mfma_gemm<256, 32, 1, 4, 1, false, 2, 3><<<dim3(1024, 1), 256, 0, stream>>>(
        xA, wr2b, bl2, Yp, nullptr, xB, 128, 0);

    // ---- L3: din=256, dout=128; proj split-K=2 ----
    mfma_gemm<128, 32, 2, 2, 0, false, 2, 2><<<dim3(32, 2), 256, 0, stream>>>(
        xB, wl3b, nullptr, Yp, nullptr, nullptr, 256, 128);
    mfma_gemm<128, 32, 2, 2, 1, false, 2, 4><<<dim3(1024, 1), 256, 0, stream>>>(
        xB, wr3b, bl3, Yp, nullptr, xA, 256, 0);

    // ---- L4: din=128, dout=256 + ReLU -> fp32 out; proj split-K=2 ----
    mfma_gemm<256, 32, 1, 4, 0, false, 2, 2><<<dim3(32, 2), 256, 0, stream>>>(
        xA, wl4b, nullptr, Yp, nullptr, nullptr, 128, 64);
    mfma_gemm<256, 32, 1, 4, 2, false, 2, 3><<<dim3(1024, 1), 256, 0, stream>>>(
        xA, wr4b, bl4, Yp, out, nullptr, 128, 0);
}

// Round 10
// 112.662 us; speedup vs baseline: 2.4661x; 1.7759x over previous
//
#include <hip/hip_runtime.h>
#include <math.h>

// ---------------------------------------------------------------------------
// Encoder_Flows on MI355X — 8 dispatches. R5 (116.9us) mains verbatim.
//   prep  : blocks 0-31 proj1 (dbuf-pipelined staged GEMM -> YT1 bf16),
//           blocks 32-351 weight fp32->bf16 cvt, + tuple scalar.
//   proj_L: 32 blocks, dbuf-pipelined staged GEMM -> YT_L bf16 (latency-bound
//           regime: 1 block/CU -> double-buffer + 2-deep prefetch halves the
//           serial k-chain; one barrier per step).
//   main_L: R5 core verbatim: 1024x32-row blocks, 2-barrier staged GEMM,
//           head blocks (i0<1024) scan-GEMM agg from bf16 YT (256KB staged,
//           coalesced), bias+agg+row-L2-norm -> bf16 x (L4: relu->fp32 out).
// Laws from R6-R9: head-extra work must be coalesced+small (bf16 YT only);
// no direct-frag global loads; no in-block layer chaining; mains untouched.
// ---------------------------------------------------------------------------

typedef __attribute__((ext_vector_type(8))) short short8;
typedef __attribute__((ext_vector_type(4))) float f32x4;

constexpr int NROWS = 32768;
constexpr int KROWS = 1024;

static __device__ __forceinline__ unsigned short f2bf(float f) {
    unsigned int u = __float_as_uint(f);
    return (unsigned short)((u + 0x7fffu + ((u >> 16) & 1u)) >> 16);
}

// ---- register staging helpers (tile ROWS x 64, XOR-swizzled LDS) ----------
template<int ROWS>
struct RegsBF {
    short8 v[ROWS / 32];
    __device__ __forceinline__ void load(const unsigned short* src, int ld,
                                         int r0, int k0, int t) {
#pragma unroll
        for (int j = 0; j < ROWS / 32; ++j) {
            int idx = j * 256 + t; int r = idx >> 3, f = idx & 7;
            v[j] = *reinterpret_cast<const short8*>(
                src + (size_t)(r0 + r) * ld + k0 + f * 8);
        }
    }
    __device__ __forceinline__ void store(unsigned short* buf, int t) {
#pragma unroll
        for (int j = 0; j < ROWS / 32; ++j) {
            int idx = j * 256 + t; int r = idx >> 3, f = idx & 7;
            int off = (r * 128 + f * 16) ^ ((r & 7) << 4);
            *reinterpret_cast<short8*>((char*)buf + off) = v[j];
        }
    }
};

template<int ROWS>
struct RegsF32 {
    float4 v[ROWS / 16];
    __device__ __forceinline__ void load(const float* src, int ld,
                                         int r0, int k0, int t) {
#pragma unroll
        for (int j = 0; j < ROWS / 32; ++j) {
            int idx = j * 256 + t; int r = idx >> 3, f = idx & 7;
            const float* p = src + (size_t)(r0 + r) * ld + k0 + f * 8;
            v[2 * j]     = *reinterpret_cast<const float4*>(p);
            v[2 * j + 1] = *reinterpret_cast<const float4*>(p + 4);
        }
    }
    __device__ __forceinline__ void store(unsigned short* buf, int t) {
#pragma unroll
        for (int j = 0; j < ROWS / 32; ++j) {
            int idx = j * 256 + t; int r = idx >> 3, f = idx & 7;
            float4 a = v[2 * j], b = v[2 * j + 1];
            short8 s;
            s[0] = (short)f2bf(a.x); s[1] = (short)f2bf(a.y);
            s[2] = (short)f2bf(a.z); s[3] = (short)f2bf(a.w);
            s[4] = (short)f2bf(b.x); s[5] = (short)f2bf(b.y);
            s[6] = (short)f2bf(b.z); s[7] = (short)f2bf(b.w);
            int off = (r * 128 + f * 16) ^ ((r & 7) << 4);
            *reinterpret_cast<short8*>((char*)buf + off) = s;
        }
    }
};

// ---------------------------------------------------------------------------
// Proj body: Y^T = (X[i0..i0+32) @ W^T)^T, dbuf-pipelined (latency regime).
//   2 LDS buffer pairs; load(kt+2) issued at step kt; one barrier/step.
// ---------------------------------------------------------------------------
template<int DIN, int DOUT, bool AFP32, bool BFP32>
__device__ __forceinline__ void proj_dbuf(const void* __restrict__ Xv,
    const void* __restrict__ Wv, unsigned short* __restrict__ YT, int i0, int t,
    unsigned short* Ab0, unsigned short* Ab1,
    unsigned short* Bb0, unsigned short* Bb1)
{
    constexpr int WN = DOUT / 64, WM = 4 / WN, FM = DOUT / 128, NT = DIN / 64;
    const int wv = t >> 6, lane = t & 63, wr_ = wv / WN, wc = wv % WN;
    f32x4 acc[FM][4];
#pragma unroll
    for (int fi = 0; fi < FM; ++fi)
#pragma unroll
        for (int fj = 0; fj < 4; ++fj) acc[fi][fj] = (f32x4){0.f, 0.f, 0.f, 0.f};

    RegsF32<32>  arf; RegsBF<32>  arb;
    RegsF32<DOUT> brf; RegsBF<DOUT> brb;
    // prologue: k=0 -> buf0; issue k=1 loads
    if (AFP32) arf.load((const float*)Xv, DIN, i0, 0, t);
    else       arb.load((const unsigned short*)Xv, DIN, i0, 0, t);
    if (BFP32) brf.load((const float*)Wv, DIN, 0, 0, t);
    else       brb.load((const unsigned short*)Wv, DIN, 0, 0, t);
    if (AFP32) arf.store(Ab0, t); else arb.store(Ab0, t);
    if (BFP32) brf.store(Bb0, t); else brb.store(Bb0, t);
    if (NT > 1) {
        if (AFP32) arf.load((const float*)Xv, DIN, i0, 64, t);
        else       arb.load((const unsigned short*)Xv, DIN, i0, 64, t);
        if (BFP32) brf.load((const float*)Wv, DIN, 0, 64, t);
        else       brb.load((const unsigned short*)Wv, DIN, 0, 64, t);
    }
    __syncthreads();

    for (int kt = 0; kt < NT; ++kt) {
        const unsigned short* Ac = (kt & 1) ? Ab1 : Ab0;
        const unsigned short* Bc = (kt & 1) ? Bb1 : Bb0;
#pragma unroll
        for (int kk = 0; kk < 2; ++kk) {
            short8 a[FM], b[4];
#pragma unroll
            for (int fi = 0; fi < FM; ++fi) {
                const int rA = wr_ * (32 / WM) + fi * 16 + (lane & 15);
                const int off = (rA * 128 + kk * 64 + (lane >> 4) * 16) ^ ((rA & 7) << 4);
                a[fi] = *reinterpret_cast<const short8*>((const char*)Ac + off);
            }
#pragma unroll
            for (int fj = 0; fj < 4; ++fj) {
                const int rB = wc * 64 + fj * 16 + (lane & 15);
                const int off = (rB * 128 + kk * 64 + (lane >> 4) * 16) ^ ((rB & 7) << 4);
                b[fj] = *reinterpret_cast<const short8*>((const char*)Bc + off);
            }
#pragma unroll
            for (int fi = 0; fi < FM; ++fi)
#pragma unroll
                for (int fj = 0; fj < 4; ++fj)
                    acc[fi][fj] = __builtin_amdgcn_mfma_f32_16x16x32_bf16(
                        a[fi], b[fj], acc[fi][fj], 0, 0, 0);
        }
        if (kt + 1 < NT) {
            unsigned short* An = (kt & 1) ? Ab0 : Ab1;
            unsigned short* Bn = (kt & 1) ? Bb0 : Bb1;
            if (AFP32) arf.store(An, t); else arb.store(An, t);
            if (BFP32) brf.store(Bn, t); else brb.store(Bn, t);
            if (kt + 2 < NT) {
                const int kn = (kt + 2) * 64;
                if (AFP32) arf.load((const float*)Xv, DIN, i0, kn, t);
                else       arb.load((const unsigned short*)Xv, DIN, i0, kn, t);
                if (BFP32) brf.load((const float*)Wv, DIN, 0, kn, t);
                else       brb.load((const unsigned short*)Wv, DIN, 0, kn, t);
            }
        }
        __syncthreads();
    }
    // epilogue: YT[col][i0+row] bf16, ushort4 over 4 regs (C/D m89 layout)
#pragma unroll
    for (int fi = 0; fi < FM; ++fi)
#pragma unroll
        for (int fj = 0; fj < 4; ++fj) {
            const int rl0 = wr_ * (32 / WM) + fi * 16 + ((lane >> 4) << 2);
            const int cl  = wc * 64 + fj * 16 + (lane & 15);
            ushort4 y;
            y.x = f2bf(acc[fi][fj][0]); y.y = f2bf(acc[fi][fj][1]);
            y.z = f2bf(acc[fi][fj][2]); y.w = f2bf(acc[fi][fj][3]);
            *reinterpret_cast<ushort4*>(YT + (size_t)cl * KROWS + i0 + rl0) = y;
        }
}

// ---------------------------------------------------------------------------
// prep: blocks [0,32) proj1 -> YT1; blocks [32,352) weight cvt; scalar.
// ---------------------------------------------------------------------------
__global__ __launch_bounds__(256, 2)
void prep_kernel(const float* __restrict__ flow, const float* __restrict__ wl1,
                 const float* __restrict__ wr1, const float* __restrict__ wl2,
                 const float* __restrict__ wr2, const float* __restrict__ wl3,
                 const float* __restrict__ wr3, const float* __restrict__ wl4,
                 const float* __restrict__ wr4,
                 unsigned short* __restrict__ wbf,
                 unsigned short* __restrict__ YT1, float* __restrict__ outscalar)
{
    __shared__ unsigned short Ab0[32 * 64], Ab1[32 * 64];
    __shared__ unsigned short Bb0[128 * 64], Bb1[128 * 64];
    const int t = threadIdx.x, bid = blockIdx.x;
    if (bid >= 32) {
        if (bid == 32 && t == 0) outscalar[0] = 1.0f;
        int g = (bid - 32) * 1024 + t * 4;
        const float* src; int off;
        if      (g < 131072) { src = wr1; off = g; }
        else if (g < 163840) { src = wl2; off = g - 131072; }
        else if (g < 196608) { src = wr2; off = g - 163840; }
        else if (g < 229376) { src = wl3; off = g - 196608; }
        else if (g < 262144) { src = wr3; off = g - 229376; }
        else if (g < 294912) { src = wl4; off = g - 262144; }
        else                 { src = wr4; off = g - 294912; }
        float4 v = *reinterpret_cast<const float4*>(src + off);
        ushort4 o4;
        o4.x = f2bf(v.x); o4.y = f2bf(v.y); o4.z = f2bf(v.z); o4.w = f2bf(v.w);
        *reinterpret_cast<ushort4*>(wbf + g) = o4;
        return;
    }
    proj_dbuf<1024, 128, true, true>(flow, wl1, YT1, bid * 32, t,
                                     Ab0, Ab1, Bb0, Bb1);
}

// ---- proj_L (L2-4): 32 blocks, x bf16 in, bf16 weights --------------------
template<int DIN, int DOUT>
__global__ __launch_bounds__(256, 2)
void proj_kernel(const unsigned short* __restrict__ X,
                 const unsigned short* __restrict__ W,
                 unsigned short* __restrict__ YT)
{
    __shared__ unsigned short Ab0[32 * 64], Ab1[32 * 64];
    __shared__ unsigned short Bb0[DOUT * 64], Bb1[DOUT * 64];
    proj_dbuf<DIN, DOUT, false, false>(X, W, YT, blockIdx.x * 32, threadIdx.x,
                                       Ab0, Ab1, Bb0, Bb1);
}

// ---------------------------------------------------------------------------
// main_L — R5 core VERBATIM.  MODE 1: bf16 out.  MODE 2: relu -> fp32 out.
// ---------------------------------------------------------------------------
template<int DOUT, int BM, int WM, int WN, int MODE, bool AFP32, int MINW>
__global__ __launch_bounds__(256, MINW)
void mfma_gemm(const void* __restrict__ Xv,
               const unsigned short* __restrict__ W,
               const float* __restrict__ bias,
               const unsigned short* __restrict__ YT,  // (DOUT, 1024) bf16
               float* __restrict__ outf,
               unsigned short* __restrict__ outb,
               int din)
{
    constexpr int BN = WN * 64;
    static_assert(BN == DOUT, "block must own full output rows");
    constexpr int FM = BM / (WM * 16);
    __shared__ unsigned short Abuf[BM * 64];
    __shared__ unsigned short Bbuf[BN * 64];
    __shared__ float ssred[WN * BM];

    const int t = threadIdx.x, wvid = t >> 6, lane = t & 63;
    const int wr_ = wvid / WN, wc = wvid % WN;
    const int i0 = blockIdx.x * BM;
    const int nt = din >> 6;
    const bool hasagg = (i0 < KROWS);

    // ---- agg via scan-GEMM: agg = (L @ Y)/cnt from Y^T bf16 ----
    f32x4 agg[FM][4];
#pragma unroll
    for (int fi = 0; fi < FM; ++fi)
#pragma unroll
        for (int fj = 0; fj < 4; ++fj) agg[fi][fj] = (f32x4){0.f, 0.f, 0.f, 0.f};

    if (hasagg) {
        const int nt2 = (i0 + BM + 63) >> 6;    // rows only need j < i
        RegsBF<BN> sb;
        sb.load(YT, KROWS, 0, 0, t);
        for (int kt = 0; kt < nt2; ++kt) {
            if (kt) __syncthreads();
            sb.store(Bbuf, t);
            __syncthreads();
            if (kt + 1 < nt2) sb.load(YT, KROWS, 0, (kt + 1) * 64, t);
#pragma unroll
            for (int kk = 0; kk < 2; ++kk) {
                const int jb = kt * 64 + kk * 32 + ((lane >> 4) << 3);
                short8 a[FM], b[4];
#pragma unroll
                for (int fi = 0; fi < FM; ++fi) {
                    const int irow = i0 + wr_ * (BM / WM) + fi * 16 + (lane & 15);
#pragma unroll
                    for (int e = 0; e < 8; ++e)
                        a[fi][e] = (short)((jb + e < irow) ? 0x3F80 : 0);
                }
#pragma unroll
                for (int fj = 0; fj < 4; ++fj) {
                    int rB = wc * 64 + fj * 16 + (lane & 15);
                    int off = (rB * 128 + kk * 64 + (lane >> 4) * 16) ^ ((rB & 7) << 4);
                    b[fj] = *reinterpret_cast<const short8*>((const char*)Bbuf + off);
                }
#pragma unroll
                for (int fi = 0; fi < FM; ++fi)
#pragma unroll
                    for (int fj = 0; fj < 4; ++fj)
                        agg[fi][fj] = __builtin_amdgcn_mfma_f32_16x16x32_bf16(
                            a[fi], b[fj], agg[fi][fj], 0, 0, 0);
            }
        }
#pragma unroll
        for (int fi = 0; fi < FM; ++fi)
#pragma unroll
            for (int reg = 0; reg < 4; ++reg) {
                int i_abs = i0 + wr_ * (BM / WM) + fi * 16 + ((lane >> 4) << 2) + reg;
                float inv = 1.0f / (float)(i_abs > 1 ? i_abs : 1);
#pragma unroll
                for (int fj = 0; fj < 4; ++fj) agg[fi][fj][reg] *= inv;
            }
        __syncthreads();                        // Bbuf reads done before reuse
    }

    // ---- bulk GEMM ----
    f32x4 acc[FM][4];
#pragma unroll
    for (int fi = 0; fi < FM; ++fi)
#pragma unroll
        for (int fj = 0; fj < 4; ++fj) acc[fi][fj] = (f32x4){0.f, 0.f, 0.f, 0.f};

    RegsBF<BN> brg;
    RegsF32<BM> arf;
    RegsBF<BM> arb;
    if (AFP32) arf.load((const float*)Xv, din, i0, 0, t);
    else       arb.load((const unsigned short*)Xv, din, i0, 0, t);
    brg.load(W, din, 0, 0, t);

    for (int kt = 0; kt < nt; ++kt) {
        if (kt) __syncthreads();
        if (AFP32) arf.store(Abuf, t); else arb.store(Abuf, t);
        brg.store(Bbuf, t);
        __syncthreads();
        if (kt + 1 < nt) {
            int kn = (kt + 1) * 64;
            if (AFP32) arf.load((const float*)Xv, din, i0, kn, t);
            else       arb.load((const unsigned short*)Xv, din, i0, kn, t);
            brg.load(W, din, 0, kn, t);
        }
#pragma unroll
        for (int kk = 0; kk < 2; ++kk) {
            short8 a[FM], b[4];
#pragma unroll
            for (int fi = 0; fi < FM; ++fi) {
                int rA = wr_ * (BM / WM) + fi * 16 + (lane & 15);
                int off = (rA * 128 + kk * 64 + (lane >> 4) * 16) ^ ((rA & 7) << 4);
                a[fi] = *reinterpret_cast<const short8*>((const char*)Abuf + off);
            }
#pragma unroll
            for (int fj = 0; fj < 4; ++fj) {
                int rB = wc * 64 + fj * 16 + (lane & 15);
                int off = (rB * 128 + kk * 64 + (lane >> 4) * 16) ^ ((rB & 7) << 4);
                b[fj] = *reinterpret_cast<const short8*>((const char*)Bbuf + off);
            }
#pragma unroll
            for (int fi = 0; fi < FM; ++fi)
#pragma unroll
                for (int fj = 0; fj < 4; ++fj)
                    acc[fi][fj] = __builtin_amdgcn_mfma_f32_16x16x32_bf16(
                        a[fi], b[fj], acc[fi][fj], 0, 0, 0);
        }
    }

    float bb[4];
#pragma unroll
    for (int fj = 0; fj < 4; ++fj) bb[fj] = bias[wc * 64 + fj * 16 + (lane & 15)];

#pragma unroll
    for (int fi = 0; fi < FM; ++fi)
#pragma unroll
        for (int fj = 0; fj < 4; ++fj)
#pragma unroll
            for (int reg = 0; reg < 4; ++reg)
                acc[fi][fj][reg] += bb[fj] + agg[fi][fj][reg];

    float sstot[FM][4];
#pragma unroll
    for (int fi = 0; fi < FM; ++fi)
#pragma unroll
        for (int reg = 0; reg < 4; ++reg) {
            float s = 0.f;
#pragma unroll
            for (int fj = 0; fj < 4; ++fj) {
                float v = acc[fi][fj][reg];
                s += v * v;
            }
#pragma unroll
            for (int m = 8; m >= 1; m >>= 1) s += __shfl_xor(s, m);
            if ((lane & 15) == 0) {
                int rl = wr_ * (BM / WM) + fi * 16 + ((lane >> 4) << 2) + reg;
                ssred[wc * BM + rl] = s;
            }
        }
    __syncthreads();
#pragma unroll
    for (int fi = 0; fi < FM; ++fi)
#pragma unroll
        for (int reg = 0; reg < 4; ++reg) {
            int rl = wr_ * (BM / WM) + fi * 16 + ((lane >> 4) << 2) + reg;
            float s = 0.f;
#pragma unroll
            for (int c = 0; c < WN; ++c) s += ssred[c * BM + rl];
            sstot[fi][reg] = 1.0f / fmaxf(sqrtf(s), 1e-12f);
        }

#pragma unroll
    for (int fi = 0; fi < FM; ++fi)
#pragma unroll
        for (int fj = 0; fj < 4; ++fj)
#pragma unroll
            for (int reg = 0; reg < 4; ++reg) {
                int rl = wr_ * (BM / WM) + fi * 16 + ((lane >> 4) << 2) + reg;
                int cl = wc * 64 + fj * 16 + (lane & 15);
                float v = acc[fi][fj][reg] * sstot[fi][reg];
                if (MODE == 2) {
                    v = fmaxf(v, 0.f);
                    outf[(size_t)(i0 + rl) * DOUT + cl] = v;
                } else {
                    outb[(size_t)(i0 + rl) * DOUT + cl] = f2bf(v);
                }
            }
}

extern "C" void kernel_launch(void* const* d_in, const int* in_sizes, int n_in,
                              void* d_out, int out_size, void* d_ws, size_t ws_size,
                              hipStream_t stream)
{
    const float* flow = (const float*)d_in[0];
    const float* wl1 = (const float*)d_in[1];
    const float* bl1 = (const float*)d_in[2];
    const float* wr1 = (const float*)d_in[3];
    const float* wl2 = (const float*)d_in[4];
    const float* bl2 = (const float*)d_in[5];
    const float* wr2 = (const float*)d_in[6];
    const float* wl3 = (const float*)d_in[7];
    const float* bl3 = (const float*)d_in[8];
    const float* wr3 = (const float*)d_in[9];
    const float* wl4 = (const float*)d_in[10];
    const float* bl4 = (const float*)d_in[11];
    const float* wr4 = (const float*)d_in[12];
    float* out = (float*)d_out;

    char* p = (char*)d_ws;
    unsigned short* wbf = (unsigned short*)p;  p += 1 << 20;   // 327680 bf16 used
    unsigned short* xA  = (unsigned short*)p;  p += (size_t)NROWS * 128 * 2;
    unsigned short* xB  = (unsigned short*)p;  p += (size_t)NROWS * 256 * 2;
    unsigned short* YT1 = (unsigned short*)p;  p += (size_t)128 * KROWS * 2;
    unsigned short* YT2 = (unsigned short*)p;  p += (size_t)256 * KROWS * 2;
    unsigned short* YT3 = (unsigned short*)p;  p += (size_t)128 * KROWS * 2;
    unsigned short* YT4 = (unsigned short*)p;

    const unsigned short* wr1b = wbf;
    const unsigned short* wl2b = wbf + 131072;
    const unsigned short* wr2b = wbf + 163840;
    const unsigned short* wl3b = wbf + 196608;
    const unsigned short* wr3b = wbf + 229376;
    const unsigned short* wl4b = wbf + 262144;
    const unsigned short* wr4b = wbf + 294912;

    // D1: cvt + proj1 (+ tuple scalar)
    prep_kernel<<<352, 256, 0, stream>>>(flow, wl1, wr1, wl2, wr2, wl3, wr3,
                                         wl4, wr4, wbf, YT1,
                                         out + (size_t)NROWS * 256);
    // D2: main L1 (din=1024, fp32 A)
    mfma_gemm<128, 32, 2, 2, 1, true , 4><<<1024, 256, 0, stream>>>(
        flow, wr1b, bl1, YT1, nullptr, xA, 1024);
    // D3-4: L2
    proj_kernel<128, 256><<<32, 256, 0, stream>>>(xA, wl2b, YT2);
    mfma_gemm<256, 32, 1, 4, 1, false, 3><<<1024, 256, 0, stream>>>(
        xA, wr2b, bl2, YT2, nullptr, xB, 128);
    // D5-6: L3
    proj_kernel<256, 128><<<32, 256, 0, stream>>>(xB, wl3b, YT3);
    mfma_gemm<128, 32, 2, 2, 1, false, 4><<<1024, 256, 0, stream>>>(
        xB, wr3b, bl3, YT3, nullptr, xA, 256);
    // D7-8: L4 + relu -> fp32 out
    proj_kernel<128, 256><<<32, 256, 0, stream>>>(xA, wl4b, YT4);
    mfma_gemm<256, 32, 1, 4, 2, false, 3><<<1024, 256, 0, stream>>>(
        xA, wr4b, bl4, YT4, out, nullptr, 128);
}